// Round 11
// baseline (15280.151 us; speedup 1.0000x reference)
//
#include <hip/hip_runtime.h>
#include <hip/hip_bf16.h>

#define BB 32
#define SS 128
#define CC 128
#define HH 128
#define OO 64

typedef _Float16 f16;
typedef f16 h2 __attribute__((ext_vector_type(2)));
typedef unsigned u32x4 __attribute__((ext_vector_type(4)));   // 4 packed f16x2 pairs

__device__ __forceinline__ float sigmoidf_(float x) {
    return 1.0f / (1.0f + __expf(-x));
}
__device__ __forceinline__ float tanh_fast_(float x) {
    return 1.0f - 2.0f / (__expf(2.0f * x) + 1.0f);  // |x| small here, no overflow
}

// Quad butterfly add on the VALU pipe. 0xB1 = xor1, 0x4E = xor2 (quad_perm).
template <int CTRL>
__device__ __forceinline__ float dpp_add(float v) {
    int m = __builtin_amdgcn_update_dpp(0, __builtin_bit_cast(int, v),
                                        CTRL, 0xF, 0xF, true);
    return v + __builtin_bit_cast(float, m);
}

__device__ __forceinline__ h2 as_h2(unsigned u) { return __builtin_bit_cast(h2, u); }

__device__ __forceinline__ unsigned pack2f(float a, float b) {
    h2 v; v[0] = (f16)a; v[1] = (f16)b;
    return __builtin_bit_cast(unsigned, v);
}
__device__ __forceinline__ u32x4 packrow8(const float* p) {
    u32x4 r;
    r.x = pack2f(p[0], p[1]);
    r.y = pack2f(p[2], p[3]);
    r.z = pack2f(p[4], p[5]);
    r.w = pack2f(p[6], p[7]);
    return r;
}

// 8-elem f16 dot, f32 accumulate; all operands pre-packed f16x2 pairs.
__device__ __forceinline__ float dot4x2(u32x4 w, u32x4 h, float acc) {
    acc = __builtin_amdgcn_fdot2(as_h2(w.x), as_h2(h.x), acc, false);
    acc = __builtin_amdgcn_fdot2(as_h2(w.y), as_h2(h.y), acc, false);
    acc = __builtin_amdgcn_fdot2(as_h2(w.z), as_h2(h.z), acc, false);
    acc = __builtin_amdgcn_fdot2(as_h2(w.w), as_h2(h.w), acc, false);
    return acc;
}

// ROUND-11 STRUCTURE: one workgroup per BATCH, running BOTH direction chains
// (forward + backward) in the same threads. R5-R10 established the step is
// serial-LATENCY-bound (~1260 cyc/step: ds round-trip + barrier + trans
// chain; every issue-reduction change was flat). Two independent chains per
// thread fill each other's stall shadows. 32 WGs x 512 threads; thread
// (j = t>>2, q = t&3) does gate rows j/j+128/j+256, quarter q, both dirs.
// Weights: 24 named u32x4 = 96 VGPRs packed f16 pairs, asm-pinned; LDS
// inflated >80KB + waves_per_eu(2,2) keeps the 256-VGPR allocator budget
// (R8) so the set stays resident. h in LDS as f16, quarter-skewed (q*40
// halves) -> conflict-free b128 broadcasts. 1 barrier/step for both chains.
__global__
__attribute__((amdgpu_flat_work_group_size(512, 512), amdgpu_waves_per_eu(2, 2)))
void gru_chain_kernel(
    const float* __restrict__ x,       // (B,S,C)
    const float* __restrict__ h_prev,  // (2,B,H)
    const float* __restrict__ Wih_f, const float* __restrict__ Whh_f,
    const float* __restrict__ bih_f, const float* __restrict__ bhh_f,
    const float* __restrict__ Wih_b, const float* __restrict__ Whh_b,
    const float* __restrict__ bih_b, const float* __restrict__ bhh_b,
    float* __restrict__ hsnap)         // (2, C, B, H) column-end snapshots
{
    const int b = blockIdx.x;      // batch 0..31 (both directions here)
    const int t = threadIdx.x;     // 0..511
    const int j = t >> 2;          // hidden index 0..127
    const int q = t & 3;           // quarter of the dot

    // xs padded: total LDS > 80KB -> 1 block/CU -> 256-VGPR budget.
    __shared__ float xs[SS * CC + 4608];
    __shared__ __align__(16) f16 hbufF[2][160];   // quarter q at half-offset q*40
    __shared__ __align__(16) f16 hbufB[2][160];

    // stage x[b] (16384 contiguous floats) into LDS, coalesced float4
    {
        const float4* xb4 = reinterpret_cast<const float4*>(x + (size_t)b * SS * CC);
        float4* xs4 = reinterpret_cast<float4*>(xs);
        #pragma unroll
        for (int i = 0; i < 8; ++i) xs4[t + i * 512] = xb4[t + i * 512];
    }

    // 24 NAMED u32x4 (96 VGPRs): rows j, j+128, j+256, quarter q, both dirs
    const float* rowr_f = Whh_f + (j          ) * HH + q * 32;
    const float* rowz_f = Whh_f + (j +     HH ) * HH + q * 32;
    const float* rown_f = Whh_f + (j + 2 * HH ) * HH + q * 32;
    const float* rowr_b = Whh_b + (j          ) * HH + q * 32;
    const float* rowz_b = Whh_b + (j +     HH ) * HH + q * 32;
    const float* rown_b = Whh_b + (j + 2 * HH ) * HH + q * 32;
    u32x4 wrA_f = packrow8(rowr_f +  0), wrB_f = packrow8(rowr_f +  8),
          wrC_f = packrow8(rowr_f + 16), wrD_f = packrow8(rowr_f + 24);
    u32x4 wzA_f = packrow8(rowz_f +  0), wzB_f = packrow8(rowz_f +  8),
          wzC_f = packrow8(rowz_f + 16), wzD_f = packrow8(rowz_f + 24);
    u32x4 wnA_f = packrow8(rown_f +  0), wnB_f = packrow8(rown_f +  8),
          wnC_f = packrow8(rown_f + 16), wnD_f = packrow8(rown_f + 24);
    u32x4 wrA_b = packrow8(rowr_b +  0), wrB_b = packrow8(rowr_b +  8),
          wrC_b = packrow8(rowr_b + 16), wrD_b = packrow8(rowr_b + 24);
    u32x4 wzA_b = packrow8(rowz_b +  0), wzB_b = packrow8(rowz_b +  8),
          wzC_b = packrow8(rowz_b + 16), wzD_b = packrow8(rowz_b + 24);
    u32x4 wnA_b = packrow8(rown_b +  0), wnB_b = packrow8(rown_b +  8),
          wnC_b = packrow8(rown_b + 16), wnD_b = packrow8(rown_b + 24);
    asm volatile("" : "+v"(wrA_f), "+v"(wrB_f), "+v"(wrC_f), "+v"(wrD_f),
                      "+v"(wzA_f), "+v"(wzB_f), "+v"(wzC_f), "+v"(wzD_f),
                      "+v"(wnA_f), "+v"(wnB_f), "+v"(wnC_f), "+v"(wnD_f));
    asm volatile("" : "+v"(wrA_b), "+v"(wrB_b), "+v"(wrC_b), "+v"(wrD_b),
                      "+v"(wzA_b), "+v"(wzB_b), "+v"(wzC_b), "+v"(wzD_b),
                      "+v"(wnA_b), "+v"(wnB_b), "+v"(wnC_b), "+v"(wnD_b));

    const float wih_r_f = Wih_f[j];
    const float wih_z_f = Wih_f[j + HH];
    const float wih_n_f = Wih_f[j + 2 * HH];
    const float brz_r4_f = 0.25f * (bih_f[j]      + bhh_f[j]);
    const float brz_z4_f = 0.25f * (bih_f[j + HH] + bhh_f[j + HH]);
    const float bhh_n4_f = 0.25f * bhh_f[j + 2 * HH];
    const float bih_n_f  = bih_f[j + 2 * HH];

    const float wih_r_b = Wih_b[j];
    const float wih_z_b = Wih_b[j + HH];
    const float wih_n_b = Wih_b[j + 2 * HH];
    const float brz_r4_b = 0.25f * (bih_b[j]      + bhh_b[j]);
    const float brz_z4_b = 0.25f * (bih_b[j + HH] + bhh_b[j + HH]);
    const float bhh_n4_b = 0.25f * bhh_b[j + 2 * HH];
    const float bih_n_b  = bih_b[j + 2 * HH];

    float hp_f = h_prev[(0 * BB + b) * HH + j];   // f32 carries (all 4 lanes)
    float hp_b = h_prev[(1 * BB + b) * HH + j];
    const int hwr = ((j >> 5) * 40) + (j & 31);   // skewed write slot (halves)
    if (q == 0) { hbufF[0][hwr] = (f16)hp_f; hbufB[0][hwr] = (f16)hp_b; }
    __syncthreads();

    // One paired GRU step: both chains read SRC, write DST, one barrier.
#define GSTEP(SRC, DST, TSS)                                                   \
    {                                                                          \
        const float xv_f = xs[(TSS) * CC + c];                                 \
        const float xv_b = xs[(SS - 1 - (TSS)) * CC + c];                      \
        const u32x4* hf = reinterpret_cast<const u32x4*>(&hbufF[SRC][q * 40]); \
        const u32x4* hb = reinterpret_cast<const u32x4*>(&hbufB[SRC][q * 40]); \
        const u32x4 f0 = hf[0], f1 = hf[1], f2 = hf[2], f3 = hf[3];            \
        const u32x4 g0 = hb[0], g1 = hb[1], g2 = hb[2], g3 = hb[3];            \
        float ra_f = dot4x2(wrA_f, f0, brz_r4_f), rb_f = dot4x2(wrC_f, f2, 0.f); \
        float za_f = dot4x2(wzA_f, f0, brz_z4_f), zb_f = dot4x2(wzC_f, f2, 0.f); \
        float na_f = dot4x2(wnA_f, f0, bhh_n4_f), nb_f = dot4x2(wnC_f, f2, 0.f); \
        float ra_b = dot4x2(wrA_b, g0, brz_r4_b), rb_b = dot4x2(wrC_b, g2, 0.f); \
        float za_b = dot4x2(wzA_b, g0, brz_z4_b), zb_b = dot4x2(wzC_b, g2, 0.f); \
        float na_b = dot4x2(wnA_b, g0, bhh_n4_b), nb_b = dot4x2(wnC_b, g2, 0.f); \
        ra_f = dot4x2(wrB_f, f1, ra_f);  rb_f = dot4x2(wrD_f, f3, rb_f);       \
        za_f = dot4x2(wzB_f, f1, za_f);  zb_f = dot4x2(wzD_f, f3, zb_f);       \
        na_f = dot4x2(wnB_f, f1, na_f);  nb_f = dot4x2(wnD_f, f3, nb_f);       \
        ra_b = dot4x2(wrB_b, g1, ra_b);  rb_b = dot4x2(wrD_b, g3, rb_b);       \
        za_b = dot4x2(wzB_b, g1, za_b);  zb_b = dot4x2(wzD_b, g3, zb_b);       \
        na_b = dot4x2(wnB_b, g1, na_b);  nb_b = dot4x2(wnD_b, g3, nb_b);       \
        float sr_f = ra_f + rb_f, sz_f = za_f + zb_f, sn_f = na_f + nb_f;      \
        float sr_b = ra_b + rb_b, sz_b = za_b + zb_b, sn_b = na_b + nb_b;      \
        sr_f = dpp_add<0xB1>(sr_f); sr_f = dpp_add<0x4E>(sr_f);                \
        sz_f = dpp_add<0xB1>(sz_f); sz_f = dpp_add<0x4E>(sz_f);                \
        sn_f = dpp_add<0xB1>(sn_f); sn_f = dpp_add<0x4E>(sn_f);                \
        sr_b = dpp_add<0xB1>(sr_b); sr_b = dpp_add<0x4E>(sr_b);                \
        sz_b = dpp_add<0xB1>(sz_b); sz_b = dpp_add<0x4E>(sz_b);                \
        sn_b = dpp_add<0xB1>(sn_b); sn_b = dpp_add<0x4E>(sn_b);                \
        const float r_f = sigmoidf_(fmaf(xv_f, wih_r_f, sr_f));                \
        const float z_f = sigmoidf_(fmaf(xv_f, wih_z_f, sz_f));                \
        const float r_b = sigmoidf_(fmaf(xv_b, wih_r_b, sr_b));                \
        const float z_b = sigmoidf_(fmaf(xv_b, wih_z_b, sz_b));                \
        const float n_f = tanh_fast_(fmaf(r_f, sn_f, fmaf(xv_f, wih_n_f, bih_n_f))); \
        const float n_b = tanh_fast_(fmaf(r_b, sn_b, fmaf(xv_b, wih_n_b, bih_n_b))); \
        hp_f = fmaf(z_f, hp_f - n_f, n_f);                                     \
        hp_b = fmaf(z_b, hp_b - n_b, n_b);                                     \
        if (q == 0) { hbufF[DST][hwr] = (f16)hp_f; hbufB[DST][hwr] = (f16)hp_b; } \
        __syncthreads();                                                       \
    }

    for (int c = 0; c < CC; ++c) {
        for (int ts = 0; ts < SS; ts += 2) {
            GSTEP(0, 1, ts)        // h: buf0 -> buf1
            GSTEP(1, 0, ts + 1)    // h: buf1 -> buf0
        }
        if (q == 0) {
            hsnap[(((size_t)0 * CC + c) * BB + b) * HH + j] = hp_f;
            hsnap[(((size_t)1 * CC + c) * BB + b) * HH + j] = hp_b;
        }
    }
#undef GSTEP
}

// One block (= one wave of 64 threads) per (c,b): FC + ReLU + softmax over O=64.
__global__ __launch_bounds__(64) void fc_softmax_kernel(
    const float* __restrict__ hsnap,   // (2, C, B, H)
    const float* __restrict__ W_fc,    // (O, 2H)
    const float* __restrict__ b_fc,    // (O,)
    float* __restrict__ out)           // (B, C, O)
{
    const int cb = blockIdx.x;         // c * B + b
    const int c  = cb >> 5;
    const int b  = cb & 31;
    const int o  = threadIdx.x;        // 0..63

    __shared__ float feat[2 * HH];     // [hf, hb]
    #pragma unroll
    for (int i = 0; i < 4; ++i) {
        const int idx = i * 64 + o;            // 0..255
        const int dd  = idx >> 7;              // 0: hf, 1: hb
        const int jj  = idx & (HH - 1);
        feat[idx] = hsnap[(((size_t)dd * CC + c) * BB + b) * HH + jj];
    }
    __syncthreads();

    float acc = 0.f;
    const float4* wrow = reinterpret_cast<const float4*>(W_fc + o * 2 * HH);
    const float4* f4   = reinterpret_cast<const float4*>(feat);
    #pragma unroll
    for (int k = 0; k < 64; ++k) {
        const float4 wv = wrow[k];
        const float4 fv = f4[k];
        acc = fmaf(wv.x, fv.x, acc);
        acc = fmaf(wv.y, fv.y, acc);
        acc = fmaf(wv.z, fv.z, acc);
        acc = fmaf(wv.w, fv.w, acc);
    }
    float v = fmaxf(acc + b_fc[o], 0.0f);

    float m = v;
    #pragma unroll
    for (int off = 32; off; off >>= 1) m = fmaxf(m, __shfl_xor(m, off));
    const float e = __expf(v - m);
    float ssum = e;
    #pragma unroll
    for (int off = 32; off; off >>= 1) ssum += __shfl_xor(ssum, off);

    out[((size_t)b * CC + c) * OO + o] = e / ssum;
}

extern "C" void kernel_launch(void* const* d_in, const int* in_sizes, int n_in,
                              void* d_out, int out_size, void* d_ws, size_t ws_size,
                              hipStream_t stream) {
    const float* x      = (const float*)d_in[0];
    const float* h_prev = (const float*)d_in[1];
    const float* Wih_f  = (const float*)d_in[2];
    const float* Whh_f  = (const float*)d_in[3];
    const float* bih_f  = (const float*)d_in[4];
    const float* bhh_f  = (const float*)d_in[5];
    const float* Wih_b  = (const float*)d_in[6];
    const float* Whh_b  = (const float*)d_in[7];
    const float* bih_b  = (const float*)d_in[8];
    const float* bhh_b  = (const float*)d_in[9];
    const float* W_fc   = (const float*)d_in[10];
    const float* b_fc   = (const float*)d_in[11];
    float* out   = (float*)d_out;
    float* hsnap = (float*)d_ws;   // 2*C*B*H*4 = 4 MiB of scratch

    gru_chain_kernel<<<BB, 512, 0, stream>>>(x, h_prev, Wih_f, Whh_f, bih_f, bhh_f,
                                             Wih_b, Whh_b, bih_b, bhh_b, hsnap);
    fc_softmax_kernel<<<CC * BB, 64, 0, stream>>>(hsnap, W_fc, b_fc, out);
}

// Round 12
// 7158.586 us; speedup vs baseline: 2.1345x; 2.1345x over previous
//
#include <hip/hip_runtime.h>
#include <hip/hip_bf16.h>

#define BB 32
#define SS 128
#define CC 128
#define HH 128
#define OO 64

typedef _Float16 f16;
typedef f16 h2 __attribute__((ext_vector_type(2)));
typedef unsigned u32x4 __attribute__((ext_vector_type(4)));   // 4 packed f16x2 pairs

__device__ __forceinline__ float sigmoidf_(float x) {
    return 1.0f / (1.0f + __expf(-x));
}
__device__ __forceinline__ float tanh_fast_(float x) {
    return 1.0f - 2.0f / (__expf(2.0f * x) + 1.0f);  // |x| small here, no overflow
}

// Pair butterfly add on the VALU pipe (DPP quad_perm xor1).
__device__ __forceinline__ float dpp_add_x1(float v) {
    int m = __builtin_amdgcn_update_dpp(0, __builtin_bit_cast(int, v),
                                        0xB1, 0xF, 0xF, true);
    return v + __builtin_bit_cast(float, m);
}

__device__ __forceinline__ h2 as_h2(unsigned u) { return __builtin_bit_cast(h2, u); }

__device__ __forceinline__ unsigned pack2f(float a, float b) {
    h2 v; v[0] = (f16)a; v[1] = (f16)b;
    return __builtin_bit_cast(unsigned, v);
}
__device__ __forceinline__ u32x4 packrow8(const float* p) {
    u32x4 r;
    r.x = pack2f(p[0], p[1]);
    r.y = pack2f(p[2], p[3]);
    r.z = pack2f(p[4], p[5]);
    r.w = pack2f(p[6], p[7]);
    return r;
}

// 8-elem f16 dot, f32 accumulate; all operands pre-packed f16x2 pairs.
__device__ __forceinline__ float dot4x2(u32x4 w, u32x4 h, float acc) {
    acc = __builtin_amdgcn_fdot2(as_h2(w.x), as_h2(h.x), acc, false);
    acc = __builtin_amdgcn_fdot2(as_h2(w.y), as_h2(h.y), acc, false);
    acc = __builtin_amdgcn_fdot2(as_h2(w.z), as_h2(h.z), acc, false);
    acc = __builtin_amdgcn_fdot2(as_h2(w.w), as_h2(h.w), acc, false);
    return acc;
}

// ROUND-12 STRUCTURE: one workgroup per (direction, batch), 256 threads =
// 4 waves = 1 WAVE PER SIMD. R5-R11 established: the step is ~half aggregate
// VALU-issue and the issue half is dominated by per-wave REPLICATED overhead
// (DPP reduce stages, transcendentals, hp/cvt/misc), not MACs. Fewer
// waves/SIMD + narrower split minimizes replication: thread (j = t>>1,
// half = t&1) does gate rows j/j+128/j+256 over 64 of 128 dot elems;
// ONE dpp xor1 stage finishes the reduce (vs 2-3 stages in R5-R11).
// Per-SIMD per-step issue ~290 cyc vs ~620 in R10.
// Weights: 24 named u32x4 = 96 VGPRs packed f16 pairs, asm-pinned; LDS
// inflated >80KB -> 1 block/CU -> 256-VGPR allocator budget (R8) so the
// set stays resident. 12 independent 8-deep dot chains give the lone wave
// ILP to cover LDS latency. h halves at f16-offset half*72 -> the two b128
// broadcast addresses hit disjoint bank quads. 1 barrier/step.
__global__
__attribute__((amdgpu_flat_work_group_size(256, 256), amdgpu_waves_per_eu(1, 2)))
void gru_chain_kernel(
    const float* __restrict__ x,       // (B,S,C)
    const float* __restrict__ h_prev,  // (2,B,H)
    const float* __restrict__ Wih_f, const float* __restrict__ Whh_f,
    const float* __restrict__ bih_f, const float* __restrict__ bhh_f,
    const float* __restrict__ Wih_b, const float* __restrict__ Whh_b,
    const float* __restrict__ bih_b, const float* __restrict__ bhh_b,
    float* __restrict__ hsnap)         // (2, C, B, H) column-end snapshots
{
    const int wg   = blockIdx.x;
    const int d    = wg >> 5;      // 0 = forward, 1 = backward
    const int b    = wg & 31;
    const int t    = threadIdx.x;  // 0..255
    const int j    = t >> 1;       // hidden index 0..127
    const int half = t & 1;        // which 64-elem half of the dot

    const float* __restrict__ Wih = d ? Wih_b : Wih_f;
    const float* __restrict__ Whh = d ? Whh_b : Whh_f;
    const float* __restrict__ bih = d ? bih_b : bih_f;
    const float* __restrict__ bhh = d ? bhh_b : bhh_f;

    // xs padded: total LDS > 80KB -> 1 block/CU -> 256-VGPR budget.
    __shared__ float xs[SS * CC + 4608];
    __shared__ __align__(16) f16 hbuf[2][160];   // half at f16-offset half*72

    // stage x[b] (16384 contiguous floats) into LDS, coalesced float4
    {
        const float4* xb4 = reinterpret_cast<const float4*>(x + (size_t)b * SS * CC);
        float4* xs4 = reinterpret_cast<float4*>(xs);
        #pragma unroll
        for (int i = 0; i < 16; ++i) xs4[t + i * 256] = xb4[t + i * 256];
    }

    // 24 NAMED u32x4 (96 VGPRs) of packed f16 pairs: rows j, j+128, j+256,
    // this thread's 64-element half.
    const float* rowr = Whh + (j          ) * HH + half * 64;
    const float* rowz = Whh + (j +     HH ) * HH + half * 64;
    const float* rown = Whh + (j + 2 * HH ) * HH + half * 64;
    u32x4 wr0 = packrow8(rowr +  0), wr1 = packrow8(rowr +  8),
          wr2 = packrow8(rowr + 16), wr3 = packrow8(rowr + 24),
          wr4 = packrow8(rowr + 32), wr5 = packrow8(rowr + 40),
          wr6 = packrow8(rowr + 48), wr7 = packrow8(rowr + 56);
    u32x4 wz0 = packrow8(rowz +  0), wz1 = packrow8(rowz +  8),
          wz2 = packrow8(rowz + 16), wz3 = packrow8(rowz + 24),
          wz4 = packrow8(rowz + 32), wz5 = packrow8(rowz + 40),
          wz6 = packrow8(rowz + 48), wz7 = packrow8(rowz + 56);
    u32x4 wn0 = packrow8(rown +  0), wn1 = packrow8(rown +  8),
          wn2 = packrow8(rown + 16), wn3 = packrow8(rown + 24),
          wn4 = packrow8(rown + 32), wn5 = packrow8(rown + 40),
          wn6 = packrow8(rown + 48), wn7 = packrow8(rown + 56);
    asm volatile("" : "+v"(wr0), "+v"(wr1), "+v"(wr2), "+v"(wr3),
                      "+v"(wr4), "+v"(wr5), "+v"(wr6), "+v"(wr7),
                      "+v"(wz0), "+v"(wz1), "+v"(wz2), "+v"(wz3));
    asm volatile("" : "+v"(wz4), "+v"(wz5), "+v"(wz6), "+v"(wz7),
                      "+v"(wn0), "+v"(wn1), "+v"(wn2), "+v"(wn3),
                      "+v"(wn4), "+v"(wn5), "+v"(wn6), "+v"(wn7));

    const float wih_r = Wih[j];
    const float wih_z = Wih[j + HH];
    const float wih_n = Wih[j + 2 * HH];
    const float brz_r2 = 0.5f * (bih[j]      + bhh[j]);      // pair-seeded bias
    const float brz_z2 = 0.5f * (bih[j + HH] + bhh[j + HH]);
    const float bhh_n2 = 0.5f * bhh[j + 2 * HH];
    const float bih_n  = bih[j + 2 * HH];

    float hp = h_prev[(d * BB + b) * HH + j];    // f32 carry (both lanes)
    const int hwr = ((j >> 6) * 72) + (j & 63);  // skewed write slot (f16 idx)
    if (half == 0) hbuf[0][hwr] = (f16)hp;
    __syncthreads();

    // One GRU step: read h (f16 pairs) from hbuf[SRC], write new h to hbuf[DST].
#define GSTEP(SRC, DST, TSS)                                                   \
    {                                                                          \
        const int tt = d ? (SS - 1 - (TSS)) : (TSS);                           \
        const float xv = xs[tt * CC + c];        /* uniform broadcast read */  \
        const u32x4* hb =                                                      \
            reinterpret_cast<const u32x4*>(&hbuf[SRC][half * 72]);             \
        const u32x4 h0 = hb[0], h1 = hb[1], h2 = hb[2], h3 = hb[3],            \
                    h4 = hb[4], h5 = hb[5], h6 = hb[6], h7 = hb[7];            \
        float r0 = dot4x2(wr0, h0, brz_r2), r1 = dot4x2(wr1, h1, 0.f),         \
              r2 = dot4x2(wr2, h2, 0.f),    r3 = dot4x2(wr3, h3, 0.f);         \
        float z0 = dot4x2(wz0, h0, brz_z2), z1 = dot4x2(wz1, h1, 0.f),         \
              z2 = dot4x2(wz2, h2, 0.f),    z3 = dot4x2(wz3, h3, 0.f);         \
        float n0 = dot4x2(wn0, h0, bhh_n2), n1 = dot4x2(wn1, h1, 0.f),         \
              n2 = dot4x2(wn2, h2, 0.f),    n3 = dot4x2(wn3, h3, 0.f);         \
        r0 = dot4x2(wr4, h4, r0); r1 = dot4x2(wr5, h5, r1);                    \
        r2 = dot4x2(wr6, h6, r2); r3 = dot4x2(wr7, h7, r3);                    \
        z0 = dot4x2(wz4, h4, z0); z1 = dot4x2(wz5, h5, z1);                    \
        z2 = dot4x2(wz6, h6, z2); z3 = dot4x2(wz7, h7, z3);                    \
        n0 = dot4x2(wn4, h4, n0); n1 = dot4x2(wn5, h5, n1);                    \
        n2 = dot4x2(wn6, h6, n2); n3 = dot4x2(wn7, h7, n3);                    \
        float sr = (r0 + r1) + (r2 + r3);                                      \
        float sz = (z0 + z1) + (z2 + z3);                                      \
        float sn = (n0 + n1) + (n2 + n3);                                      \
        sr = dpp_add_x1(sr);                    /* one reduce stage */         \
        sz = dpp_add_x1(sz);                                                   \
        sn = dpp_add_x1(sn);                                                   \
        const float r = sigmoidf_(fmaf(xv, wih_r, sr));                        \
        const float z = sigmoidf_(fmaf(xv, wih_z, sz));                        \
        const float gi_n = fmaf(xv, wih_n, bih_n);                             \
        const float n = tanh_fast_(fmaf(r, sn, gi_n));                         \
        hp = fmaf(z, hp - n, n);                /* (1-z)*n + z*h  (f32) */     \
        if (half == 0) hbuf[DST][hwr] = (f16)hp;                               \
        __syncthreads();                                                       \
    }

    for (int c = 0; c < CC; ++c) {
        for (int ts = 0; ts < SS; ts += 2) {
            GSTEP(0, 1, ts)        // h: buf0 -> buf1
            GSTEP(1, 0, ts + 1)    // h: buf1 -> buf0
        }
        if (half == 0) {
            hsnap[(((size_t)d * CC + c) * BB + b) * HH + j] = hp;
        }
    }
#undef GSTEP
}

// One block (= one wave of 64 threads) per (c,b): FC + ReLU + softmax over O=64.
__global__ __launch_bounds__(64) void fc_softmax_kernel(
    const float* __restrict__ hsnap,   // (2, C, B, H)
    const float* __restrict__ W_fc,    // (O, 2H)
    const float* __restrict__ b_fc,    // (O,)
    float* __restrict__ out)           // (B, C, O)
{
    const int cb = blockIdx.x;         // c * B + b
    const int c  = cb >> 5;
    const int b  = cb & 31;
    const int o  = threadIdx.x;        // 0..63

    __shared__ float feat[2 * HH];     // [hf, hb]
    #pragma unroll
    for (int i = 0; i < 4; ++i) {
        const int idx = i * 64 + o;            // 0..255
        const int dd  = idx >> 7;              // 0: hf, 1: hb
        const int jj  = idx & (HH - 1);
        feat[idx] = hsnap[(((size_t)dd * CC + c) * BB + b) * HH + jj];
    }
    __syncthreads();

    float acc = 0.f;
    const float4* wrow = reinterpret_cast<const float4*>(W_fc + o * 2 * HH);
    const float4* f4   = reinterpret_cast<const float4*>(feat);
    #pragma unroll
    for (int k = 0; k < 64; ++k) {
        const float4 wv = wrow[k];
        const float4 fv = f4[k];
        acc = fmaf(wv.x, fv.x, acc);
        acc = fmaf(wv.y, fv.y, acc);
        acc = fmaf(wv.z, fv.z, acc);
        acc = fmaf(wv.w, fv.w, acc);
    }
    float v = fmaxf(acc + b_fc[o], 0.0f);

    float m = v;
    #pragma unroll
    for (int off = 32; off; off >>= 1) m = fmaxf(m, __shfl_xor(m, off));
    const float e = __expf(v - m);
    float ssum = e;
    #pragma unroll
    for (int off = 32; off; off >>= 1) ssum += __shfl_xor(ssum, off);

    out[((size_t)b * CC + c) * OO + o] = e / ssum;
}

extern "C" void kernel_launch(void* const* d_in, const int* in_sizes, int n_in,
                              void* d_out, int out_size, void* d_ws, size_t ws_size,
                              hipStream_t stream) {
    const float* x      = (const float*)d_in[0];
    const float* h_prev = (const float*)d_in[1];
    const float* Wih_f  = (const float*)d_in[2];
    const float* Whh_f  = (const float*)d_in[3];
    const float* bih_f  = (const float*)d_in[4];
    const float* bhh_f  = (const float*)d_in[5];
    const float* Wih_b  = (const float*)d_in[6];
    const float* Whh_b  = (const float*)d_in[7];
    const float* bih_b  = (const float*)d_in[8];
    const float* bhh_b  = (const float*)d_in[9];
    const float* W_fc   = (const float*)d_in[10];
    const float* b_fc   = (const float*)d_in[11];
    float* out   = (float*)d_out;
    float* hsnap = (float*)d_ws;   // 2*C*B*H*4 = 4 MiB of scratch

    gru_chain_kernel<<<64, 256, 0, stream>>>(x, h_prev, Wih_f, Whh_f, bih_f, bhh_f,
                                             Wih_b, Whh_b, bih_b, bhh_b, hsnap);
    fc_softmax_kernel<<<CC * BB, 64, 0, stream>>>(hsnap, W_fc, b_fc, out);
}